// Round 10
// baseline (125.903 us; speedup 1.0000x reference)
//
#include <hip/hip_runtime.h>
#include <math.h>

// Problem constants
constexpr int L  = 4096;    // seq len
constexpr int D  = 1024;    // d_model
constexpr int N  = 16;      // hiddens per channel
constexpr int NC = 64;      // chunks
constexpr int T  = L / NC;  // 64 steps per chunk
constexpr int DG = 64;      // channels per block
constexpr int G  = D / DG;  // 16 d-groups

__device__ __forceinline__ float softplus_f(float v) {
    return fmaxf(v, 0.0f) + log1pf(expf(-fabsf(v)));
}

// Fast Lambda = exp(dt*(ar + i*ai)) via HW transcendentals.
__device__ __forceinline__ void lam_fast(float ar, float ai, float dt,
                                         float& lr, float& li) {
    float e = __expf(ar * dt);
    float s, c;
    __sincosf(ai * dt, &s, &c);
    lr = e * c;
    li = e * s;
}

// State layout: s4[(c*D + d)*8 + k], k = 0..7 float4s packing the 16 complex
// states of (c,d): float4 k holds (gr[2k],gi[2k],gr[2k+1],gi[2k+1]).
// Thread (dl,q) owns k = q*2 and q*2+1 -> one contiguous 32B run per thread,
// one contiguous 2KB run per wave.

// K1: thread = (c, d, q): 4 states (n = q*4+j). Local scan, zero init.
// x staged via LDS (16 KiB). End states -> s4 (contiguous per wave).
__global__ __launch_bounds__(256, 4) void k_local(
    const float* __restrict__ x,
    const float* __restrict__ Delta,
    const float* __restrict__ A_re, const float* __restrict__ A_im,
    float4* __restrict__ s4)
{
    __shared__ float xs[T * DG];          // 16 KiB
    const int c  = blockIdx.x >> 4;       // chunk
    const int dg = blockIdx.x & 15;       // d-group
    const int t  = threadIdx.x;

    const float* xg = x + (size_t)c * T * D + dg * DG;
    #pragma unroll
    for (int it = 0; it < 4; ++it) {      // 4096 floats, float4-coalesced
        int f = t * 4 + it * 1024;
        int row = f >> 6, col = f & 63;
        *(float4*)&xs[row * DG + col] =
            *(const float4*)(xg + (size_t)row * D + col);
    }

    const int q = t & 3, dl = t >> 2;
    const int d = dg * DG + dl;
    const float dt = softplus_f(Delta[d]);
    float Lr[4], Li[4];
    {
        float4 a0 = *(const float4*)(A_re + d * N + q * 4);
        float4 a1 = *(const float4*)(A_im + d * N + q * 4);
        const float ar[4] = {a0.x, a0.y, a0.z, a0.w};
        const float ai[4] = {a1.x, a1.y, a1.z, a1.w};
        #pragma unroll
        for (int j = 0; j < 4; ++j) lam_fast(ar[j], ai[j], dt, Lr[j], Li[j]);
    }
    __syncthreads();

    float gr[4] = {0, 0, 0, 0}, gi[4] = {0, 0, 0, 0};
    #pragma unroll
    for (int i = 0; i < T; ++i) {
        float xv = xs[i * DG + dl];
        #pragma unroll
        for (int j = 0; j < 4; ++j) {
            float t2 = fmaf(-Li[j], gi[j], xv);
            float nr = fmaf(Lr[j], gr[j], t2);
            gi[j] = fmaf(Lr[j], gi[j], Li[j] * gr[j]);
            gr[j] = nr;
        }
    }
    float4* dst = s4 + ((size_t)c * D + d) * 8 + q * 2;
    dst[0] = make_float4(gr[0], gi[0], gr[1], gi[1]);
    dst[1] = make_float4(gr[2], gi[2], gr[3], gi[3]);
}

// K2: thread = (c, d, q). Fold predecessor end-states (identical recurrence
// to the old k_scan -> bitwise-identical carry), then rescan from carry,
// contract with C' = dt*C*B, butterfly-reduce over q, add D*x, store.
// blockIdx mapping: c fastest, so variable fold length is spread across CUs.
__global__ __launch_bounds__(256, 4) void k_out(
    const float* __restrict__ x,
    const float* __restrict__ Delta,
    const float* __restrict__ A_re, const float* __restrict__ A_im,
    const float* __restrict__ B_re, const float* __restrict__ B_im,
    const float* __restrict__ C_re, const float* __restrict__ C_im,
    const float* __restrict__ Dp,
    const float4* __restrict__ s4,
    float* __restrict__ out)
{
    __shared__ float xs[T * DG];          // 16 KiB
    const int c  = blockIdx.x & 63;       // chunk (fastest)
    const int dg = blockIdx.x >> 6;       // d-group
    const int t  = threadIdx.x;

    const float* xg = x + (size_t)c * T * D + dg * DG;
    #pragma unroll
    for (int it = 0; it < 4; ++it) {
        int f = t * 4 + it * 1024;
        int row = f >> 6, col = f & 63;
        *(float4*)&xs[row * DG + col] =
            *(const float4*)(xg + (size_t)row * D + col);
    }

    const int q = t & 3, dl = t >> 2;
    const int d = dg * DG + dl;
    const float dt  = softplus_f(Delta[d]);
    const float dpv = Dp[d];

    float Lr[4], Li[4], Tr[4], Ti[4], Cr[4], Ci[4];
    {
        const int pidx = d * N + q * 4;
        float4 a0 = *(const float4*)(A_re + pidx);
        float4 a1 = *(const float4*)(A_im + pidx);
        float4 b0 = *(const float4*)(B_re + pidx);
        float4 b1 = *(const float4*)(B_im + pidx);
        float4 c0 = *(const float4*)(C_re + pidx);
        float4 c1 = *(const float4*)(C_im + pidx);
        const float ar[4] = {a0.x, a0.y, a0.z, a0.w};
        const float ai[4] = {a1.x, a1.y, a1.z, a1.w};
        const float br[4] = {b0.x, b0.y, b0.z, b0.w};
        const float bi[4] = {b1.x, b1.y, b1.z, b1.w};
        const float crr[4] = {c0.x, c0.y, c0.z, c0.w};
        const float cii[4] = {c1.x, c1.y, c1.z, c1.w};
        #pragma unroll
        for (int j = 0; j < 4; ++j) {
            lam_fast(ar[j], ai[j], dt, Lr[j], Li[j]);
            // LamT = Lam^T via 6 squarings (T = 64) — identical to old k_scan
            float tr = Lr[j], ti = Li[j];
            #pragma unroll
            for (int k = 0; k < 6; ++k) {
                float nr = tr * tr - ti * ti;
                ti = 2.0f * tr * ti;
                tr = nr;
            }
            Tr[j] = tr; Ti[j] = ti;
            Cr[j] = dt * (crr[j] * br[j] - cii[j] * bi[j]);
            Ci[j] = dt * (crr[j] * bi[j] + cii[j] * br[j]);
        }
    }

    // ---- fold predecessors p = 0..c-1 (ascending, 4-deep batches) ----
    float gr[4] = {0, 0, 0, 0}, gi[4] = {0, 0, 0, 0};
    const float4* sp = s4 + (size_t)d * 8 + q * 2;   // + p*D*8 per chunk
    int p = 0;
    for (; p + 4 <= c; p += 4) {
        float4 s0[4], s1[4];
        #pragma unroll
        for (int u = 0; u < 4; ++u) {
            const float4* src = sp + (size_t)(p + u) * D * 8;
            s0[u] = src[0]; s1[u] = src[1];
        }
        #pragma unroll
        for (int u = 0; u < 4; ++u) {
            const float sx[4] = {s0[u].x, s0[u].z, s1[u].x, s1[u].z};
            const float sy[4] = {s0[u].y, s0[u].w, s1[u].y, s1[u].w};
            #pragma unroll
            for (int j = 0; j < 4; ++j) {
                float nr = fmaf(Tr[j], gr[j], fmaf(-Ti[j], gi[j], sx[j]));
                gi[j] = fmaf(Tr[j], gi[j], fmaf(Ti[j], gr[j], sy[j]));
                gr[j] = nr;
            }
        }
    }
    for (; p < c; ++p) {
        const float4* src = sp + (size_t)p * D * 8;
        float4 s0 = src[0], s1 = src[1];
        const float sx[4] = {s0.x, s0.z, s1.x, s1.z};
        const float sy[4] = {s0.y, s0.w, s1.y, s1.w};
        #pragma unroll
        for (int j = 0; j < 4; ++j) {
            float nr = fmaf(Tr[j], gr[j], fmaf(-Ti[j], gi[j], sx[j]));
            gi[j] = fmaf(Tr[j], gi[j], fmaf(Ti[j], gr[j], sy[j]));
            gr[j] = nr;
        }
    }

    float* og = out + (size_t)c * T * D + dg * DG;
    __syncthreads();

    // ---- rescan from carry, contract, store ----
    #pragma unroll
    for (int ib = 0; ib < T / 4; ++ib) {
        float keep = 0.0f;
        #pragma unroll
        for (int u = 0; u < 4; ++u) {
            int i = ib * 4 + u;
            float xv = xs[i * DG + dl];
            float acc = 0.0f;
            #pragma unroll
            for (int j = 0; j < 4; ++j) {
                float t2 = fmaf(-Li[j], gi[j], xv);
                float nr = fmaf(Lr[j], gr[j], t2);
                gi[j] = fmaf(Lr[j], gi[j], Li[j] * gr[j]);
                gr[j] = nr;
                acc = fmaf(Cr[j], gr[j], acc);
                acc = fmaf(-Ci[j], gi[j], acc);
            }
            acc += __shfl_xor(acc, 1);    // reduce over q-pairs
            acc += __shfl_xor(acc, 2);
            acc = fmaf(dpv, xv, acc);     // every lane has the full sum
            keep = (q == u) ? acc : keep; // lane q keeps iteration u==q
        }
        og[(size_t)(ib * 4 + q) * D + dl] = keep;  // all 64 lanes store
    }
}

extern "C" void kernel_launch(void* const* d_in, const int* in_sizes, int n_in,
                              void* d_out, int out_size, void* d_ws, size_t ws_size,
                              hipStream_t stream) {
    const float* x     = (const float*)d_in[0];
    const float* Delta = (const float*)d_in[1];
    const float* A_re  = (const float*)d_in[2];
    const float* A_im  = (const float*)d_in[3];
    const float* B_re  = (const float*)d_in[4];
    const float* B_im  = (const float*)d_in[5];
    const float* C_re  = (const float*)d_in[6];
    const float* C_im  = (const float*)d_in[7];
    const float* Dp    = (const float*)d_in[8];
    float* out = (float*)d_out;
    float4* s4 = (float4*)d_ws;   // NC * D * 8 float4 = 8 MiB

    k_local<<<NC * G, 256, 0, stream>>>(x, Delta, A_re, A_im, s4);
    k_out<<<NC * G, 256, 0, stream>>>(x, Delta, A_re, A_im, B_re, B_im,
                                      C_re, C_im, Dp, s4, out);
}

// Round 11
// 106.920 us; speedup vs baseline: 1.1775x; 1.1775x over previous
//
#include <hip/hip_runtime.h>
#include <math.h>

// Problem constants
constexpr int L   = 4096;   // seq len
constexpr int D   = 1024;   // d_model
constexpr int N   = 16;     // hiddens per channel
constexpr int CPB = 2;      // channels per block
constexpr int NB  = D / CPB;   // 512 blocks (2 per CU)
constexpr int NCB = 64;     // chunks per block (one per ct-thread)
constexpr int T   = L / NCB;   // 64 steps per chunk

__device__ __forceinline__ float softplus_f(float v) {
    return fmaxf(v, 0.0f) + log1pf(expf(-fabsf(v)));
}

// Fast Lambda = exp(dt*(ar + i*ai)) via HW transcendentals.
__device__ __forceinline__ void lam_fast(float ar, float ai, float dt,
                                         float& lr, float& li) {
    float e = __expf(ar * dt);
    float s, c;
    __sincosf(ai * dt, &s, &c);
    lr = e * c;
    li = e * s;
}

// One dispatch. Block owns channels [d0, d0+2) x full L. Thread t:
//   h = t&1 (n-half: 8 states), dd = (t>>1)&1 (channel), ct = t>>2 (chunk).
// Phases (all intra-block, __syncthreads only):
//   0) stage x slice into LDS xs[i][ct][dd] (32 KB)
//   1) per-thread local scan of chunk ct (T=64), summaries -> LDS sums
//   2) wave 0 lanes 0..31: serial scan over 64 chunk summaries (in-place ->
//      carry-before-chunk), identical recurrence to the old k_scan
//   3) rescan from carry, contract with C'=dt*C*B (8 in-register + 1 shfl),
//      add D*x, rotated stores (both h-lanes store alternate rows)
// d0 swizzle groups blocks so each XCD's L2 sees one contiguous 2 MB x-stripe.
__global__ __launch_bounds__(256, 2) void k_fused(
    const float* __restrict__ x,
    const float* __restrict__ Delta,
    const float* __restrict__ A_re, const float* __restrict__ A_im,
    const float* __restrict__ B_re, const float* __restrict__ B_im,
    const float* __restrict__ C_re, const float* __restrict__ C_im,
    const float* __restrict__ Dp,
    float* __restrict__ out)
{
    __shared__ float  xs[T * 128];        // [i][ct][dd]: word i*128+ct*2+dd, 32 KB
    __shared__ float2 sums[NCB * 32];     // [ct][dd*16+n], 16 KB

    const int b  = blockIdx.x;
    const int d0 = (b & 7) * 128 + (b >> 3) * 2;   // XCD-contiguous channels
    const int t  = threadIdx.x;

    // ---- phase 0: stage x[0..L) x [d0, d0+2) into LDS ----
    {
        const int sct = t & 63;           // chunk row group
        const int si  = t >> 6;           // i-quarter
        float2 v[16];
        #pragma unroll
        for (int k = 0; k < 16; ++k) {
            int l = sct * T + si * 16 + k;
            v[k] = *(const float2*)(x + (size_t)l * D + d0);
        }
        #pragma unroll
        for (int k = 0; k < 16; ++k) {
            int i = si * 16 + k;
            *(float2*)&xs[i * 128 + sct * 2] = v[k];
        }
    }

    const int h  = t & 1;
    const int dd = (t >> 1) & 1;
    const int ct = t >> 2;
    const int d  = d0 + dd;
    const float dt = softplus_f(Delta[d]);

    // ---- per-thread Lambda for its 8 states (n = h*8 .. h*8+7) ----
    float Lr[8], Li[8];
    {
        const int base = d * N + h * 8;
        float4 a0 = *(const float4*)(A_re + base);
        float4 a1 = *(const float4*)(A_re + base + 4);
        float4 m0 = *(const float4*)(A_im + base);
        float4 m1 = *(const float4*)(A_im + base + 4);
        const float ar[8] = {a0.x, a0.y, a0.z, a0.w, a1.x, a1.y, a1.z, a1.w};
        const float ai[8] = {m0.x, m0.y, m0.z, m0.w, m1.x, m1.y, m1.z, m1.w};
        #pragma unroll
        for (int j = 0; j < 8; ++j) lam_fast(ar[j], ai[j], dt, Lr[j], Li[j]);
    }
    __syncthreads();   // xs ready

    // ---- phase 1: local scan of chunk ct, zero init ----
    float gr[8] = {0, 0, 0, 0, 0, 0, 0, 0}, gi[8] = {0, 0, 0, 0, 0, 0, 0, 0};
    #pragma unroll 8
    for (int i = 0; i < T; ++i) {
        float xv = xs[i * 128 + ct * 2 + dd];
        #pragma unroll
        for (int j = 0; j < 8; ++j) {
            float t2 = fmaf(-Li[j], gi[j], xv);
            float nr = fmaf(Lr[j], gr[j], t2);
            gi[j] = fmaf(Lr[j], gi[j], Li[j] * gr[j]);
            gr[j] = nr;
        }
    }
    {
        float2* sp = &sums[ct * 32 + dd * 16 + h * 8];
        #pragma unroll
        for (int j = 0; j < 8; ++j) sp[j] = make_float2(gr[j], gi[j]);
    }
    __syncthreads();   // summaries ready

    // ---- phase 2: serial scan over chunk summaries (lanes 0..31 of wave 0)
    if (t < 32) {
        const int dd2 = t >> 4, n2 = t & 15;
        const int d2  = d0 + dd2;
        const float dt2 = softplus_f(Delta[d2]);
        float lr, li;
        lam_fast(A_re[d2 * N + n2], A_im[d2 * N + n2], dt2, lr, li);
        #pragma unroll
        for (int k = 0; k < 6; ++k) {     // Lam^64 (T = 64)
            float nr = lr * lr - li * li;
            li = 2.0f * lr * li;
            lr = nr;
        }
        float cr = 0.0f, ci = 0.0f;
        #pragma unroll
        for (int c0 = 0; c0 < NCB; c0 += 16) {
            float2 sv[16];
            #pragma unroll
            for (int u = 0; u < 16; ++u) sv[u] = sums[(c0 + u) * 32 + t];
            #pragma unroll
            for (int u = 0; u < 16; ++u) {
                sums[(c0 + u) * 32 + t] = make_float2(cr, ci);
                float nr = fmaf(lr, cr, fmaf(-li, ci, sv[u].x));
                ci = fmaf(lr, ci, fmaf(li, cr, sv[u].y));
                cr = nr;
            }
        }
    }

    // ---- phase 3 params: C' = dt*(C*B), D ----
    float Cr[8], Ci[8];
    {
        const int base = d * N + h * 8;
        float4 b0 = *(const float4*)(B_re + base);
        float4 b1 = *(const float4*)(B_re + base + 4);
        float4 e0 = *(const float4*)(B_im + base);
        float4 e1 = *(const float4*)(B_im + base + 4);
        float4 f0 = *(const float4*)(C_re + base);
        float4 f1 = *(const float4*)(C_re + base + 4);
        float4 g0 = *(const float4*)(C_im + base);
        float4 g1 = *(const float4*)(C_im + base + 4);
        const float br[8] = {b0.x, b0.y, b0.z, b0.w, b1.x, b1.y, b1.z, b1.w};
        const float bi[8] = {e0.x, e0.y, e0.z, e0.w, e1.x, e1.y, e1.z, e1.w};
        const float cr[8] = {f0.x, f0.y, f0.z, f0.w, f1.x, f1.y, f1.z, f1.w};
        const float ci[8] = {g0.x, g0.y, g0.z, g0.w, g1.x, g1.y, g1.z, g1.w};
        #pragma unroll
        for (int j = 0; j < 8; ++j) {
            Cr[j] = dt * (cr[j] * br[j] - ci[j] * bi[j]);
            Ci[j] = dt * (cr[j] * bi[j] + ci[j] * br[j]);
        }
    }
    const float dpv = Dp[d];
    __syncthreads();   // carries ready

    // ---- phase 3: rescan from carry, contract, store ----
    {
        const float2* cp = &sums[ct * 32 + dd * 16 + h * 8];
        #pragma unroll
        for (int j = 0; j < 8; ++j) { gr[j] = cp[j].x; gi[j] = cp[j].y; }
    }
    #pragma unroll 4
    for (int ib = 0; ib < T / 2; ++ib) {
        float keep = 0.0f;
        #pragma unroll
        for (int u = 0; u < 2; ++u) {
            int i = ib * 2 + u;
            float xv = xs[i * 128 + ct * 2 + dd];
            float acc = 0.0f;
            #pragma unroll
            for (int j = 0; j < 8; ++j) {
                float t2 = fmaf(-Li[j], gi[j], xv);
                float nr = fmaf(Lr[j], gr[j], t2);
                gi[j] = fmaf(Lr[j], gi[j], Li[j] * gr[j]);
                gr[j] = nr;
                acc = fmaf(Cr[j], gr[j], acc);
                acc = fmaf(-Ci[j], gi[j], acc);
            }
            acc += __shfl_xor(acc, 1);    // combine the two n-halves (h^1)
            acc = fmaf(dpv, xv, acc);     // both h-lanes hold the full value
            keep = (h == u) ? acc : keep; // lane h keeps row parity u==h
        }
        out[(size_t)(ct * T + ib * 2 + h) * D + d] = keep;  // all lanes store
    }
}

extern "C" void kernel_launch(void* const* d_in, const int* in_sizes, int n_in,
                              void* d_out, int out_size, void* d_ws, size_t ws_size,
                              hipStream_t stream) {
    const float* x     = (const float*)d_in[0];
    const float* Delta = (const float*)d_in[1];
    const float* A_re  = (const float*)d_in[2];
    const float* A_im  = (const float*)d_in[3];
    const float* B_re  = (const float*)d_in[4];
    const float* B_im  = (const float*)d_in[5];
    const float* C_re  = (const float*)d_in[6];
    const float* C_im  = (const float*)d_in[7];
    const float* Dp    = (const float*)d_in[8];
    float* out = (float*)d_out;

    k_fused<<<NB, 256, 0, stream>>>(x, Delta, A_re, A_im, B_re, B_im,
                                    C_re, C_im, Dp, out);
}

// Round 12
// 105.991 us; speedup vs baseline: 1.1879x; 1.0088x over previous
//
#include <hip/hip_runtime.h>
#include <math.h>

// Problem constants
constexpr int L   = 4096;   // seq len
constexpr int D   = 1024;   // d_model
constexpr int N   = 16;     // hiddens per channel
constexpr int CPB = 2;      // channels per block
constexpr int NB  = D / CPB;   // 512 blocks (2 per CU)
constexpr int NCB = 128;    // chunks per block
constexpr int T   = L / NCB;   // 32 steps per chunk
constexpr int NT  = 512;    // threads per block

typedef float v2 __attribute__((ext_vector_type(2)));

__device__ __forceinline__ float softplus_f(float v) {
    return fmaxf(v, 0.0f) + log1pf(expf(-fabsf(v)));
}

// Fast Lambda = exp(dt*(ar + i*ai)) via HW transcendentals.
__device__ __forceinline__ void lam_fast(float ar, float ai, float dt,
                                         float& lr, float& li) {
    float e = __expf(ar * dt);
    float s, c;
    __sincosf(ai * dt, &s, &c);
    lr = e * c;
    li = e * s;
}

__device__ __forceinline__ v2 vfma(v2 a, v2 b, v2 c) {
    return __builtin_elementwise_fma(a, b, c);
}

// One dispatch. Block owns channels [d0, d0+2) x full L; 512 threads.
// Thread t: h = t&1 (n-half, 8 states), dd = (t>>1)&1 (channel), ct = t>>2
// (chunk, 128 per block, T=32 steps each). States held as 4 float2 pairs ->
// v_pk_fma_f32. Phases (intra-block only):
//   0) stage x slice into LDS xs[il][ct][dd] (32 KB)
//   1) local scan of chunk ct (zero init), summaries -> sums[ct][dd*16+n]
//   2) lanes 0..31 of wave 0: serial scan over 128 chunk summaries in LDS
//   3) rescan from carry, contract C'=dt*C*B (pairs + horizontal + h-shfl),
//      add D*x, rotated full-lane stores
// d0 swizzle: blocks b%8==k all see one contiguous 128-channel stripe -> each
// XCD's L2 caches a 2 MB x-stripe; HBM fetch stays ~16 MB.
__global__ __launch_bounds__(NT, 4) void k_fused(
    const float* __restrict__ x,
    const float* __restrict__ Delta,
    const float* __restrict__ A_re, const float* __restrict__ A_im,
    const float* __restrict__ B_re, const float* __restrict__ B_im,
    const float* __restrict__ C_re, const float* __restrict__ C_im,
    const float* __restrict__ Dp,
    float* __restrict__ out)
{
    __shared__ float  xs[T * 256];        // [il][ct][dd]: word il*256+ct*2+dd
    __shared__ float2 sums[NCB * 32];     // [ct][dd*16+n], 32 KB

    const int b  = blockIdx.x;
    const int d0 = (b & 7) * 128 + (b >> 3) * 2;   // XCD-contiguous channels
    const int t  = threadIdx.x;

    // ---- phase 0: stage x[0..L) x [d0, d0+2) into LDS ----
    {
        const int sct = t & 127;          // chunk
        const int si  = t >> 7;           // quarter of the chunk
        float2 v[8];
        #pragma unroll
        for (int k = 0; k < 8; ++k) {
            int l = sct * T + si * 8 + k;
            v[k] = *(const float2*)(x + (size_t)l * D + d0);
        }
        #pragma unroll
        for (int k = 0; k < 8; ++k) {
            int il = si * 8 + k;          // il < 32
            *(float2*)&xs[il * 256 + sct * 2] = v[k];
        }
    }

    const int h  = t & 1;
    const int dd = (t >> 1) & 1;
    const int ct = t >> 2;
    const int d  = d0 + dd;
    const float dt = softplus_f(Delta[d]);

    // ---- per-thread Lambda for its 8 states (n = h*8..h*8+7), packed ----
    v2 LR[4], LI[4];
    {
        const int base = d * N + h * 8;
        float4 a0 = *(const float4*)(A_re + base);
        float4 a1 = *(const float4*)(A_re + base + 4);
        float4 m0 = *(const float4*)(A_im + base);
        float4 m1 = *(const float4*)(A_im + base + 4);
        const float ar[8] = {a0.x, a0.y, a0.z, a0.w, a1.x, a1.y, a1.z, a1.w};
        const float ai[8] = {m0.x, m0.y, m0.z, m0.w, m1.x, m1.y, m1.z, m1.w};
        #pragma unroll
        for (int p = 0; p < 4; ++p) {
            float lr0, li0, lr1, li1;
            lam_fast(ar[2 * p], ai[2 * p], dt, lr0, li0);
            lam_fast(ar[2 * p + 1], ai[2 * p + 1], dt, lr1, li1);
            LR[p] = (v2){lr0, lr1};
            LI[p] = (v2){li0, li1};
        }
    }
    __syncthreads();   // xs ready

    // ---- phase 1: local scan of chunk ct, zero init ----
    v2 GR[4] = {(v2)0, (v2)0, (v2)0, (v2)0};
    v2 GI[4] = {(v2)0, (v2)0, (v2)0, (v2)0};
    #pragma unroll 4
    for (int i = 0; i < T; ++i) {
        float xv = xs[i * 256 + ct * 2 + dd];
        v2 XV = (v2){xv, xv};
        #pragma unroll
        for (int p = 0; p < 4; ++p) {
            v2 t2 = vfma(-LI[p], GI[p], XV);
            v2 nr = vfma(LR[p], GR[p], t2);
            GI[p] = vfma(LR[p], GI[p], LI[p] * GR[p]);
            GR[p] = nr;
        }
    }
    {
        float2* sp = &sums[ct * 32 + dd * 16 + h * 8];
        #pragma unroll
        for (int p = 0; p < 4; ++p) {
            sp[2 * p]     = make_float2(GR[p].x, GI[p].x);
            sp[2 * p + 1] = make_float2(GR[p].y, GI[p].y);
        }
    }
    __syncthreads();   // summaries ready

    // ---- phase 2: serial scan over chunk summaries (lanes 0..31, wave 0) --
    if (t < 32) {
        const int dd2 = t >> 4, n2 = t & 15;
        const int d2  = d0 + dd2;
        const float dt2 = softplus_f(Delta[d2]);
        float lr, li;
        lam_fast(A_re[d2 * N + n2], A_im[d2 * N + n2], dt2, lr, li);
        #pragma unroll
        for (int k = 0; k < 5; ++k) {     // Lam^32 (T = 32)
            float nr = lr * lr - li * li;
            li = 2.0f * lr * li;
            lr = nr;
        }
        float cr = 0.0f, ci = 0.0f;
        #pragma unroll
        for (int c0 = 0; c0 < NCB; c0 += 16) {
            float2 sv[16];
            #pragma unroll
            for (int u = 0; u < 16; ++u) sv[u] = sums[(c0 + u) * 32 + t];
            #pragma unroll
            for (int u = 0; u < 16; ++u) {
                sums[(c0 + u) * 32 + t] = make_float2(cr, ci);
                float nr = fmaf(lr, cr, fmaf(-li, ci, sv[u].x));
                ci = fmaf(lr, ci, fmaf(li, cr, sv[u].y));
                cr = nr;
            }
        }
    }

    // ---- phase 3 params: C' = dt*(C*B), D (packed) ----
    v2 CR[4], CI[4];
    {
        const int base = d * N + h * 8;
        float4 b0 = *(const float4*)(B_re + base);
        float4 b1 = *(const float4*)(B_re + base + 4);
        float4 e0 = *(const float4*)(B_im + base);
        float4 e1 = *(const float4*)(B_im + base + 4);
        float4 f0 = *(const float4*)(C_re + base);
        float4 f1 = *(const float4*)(C_re + base + 4);
        float4 g0 = *(const float4*)(C_im + base);
        float4 g1 = *(const float4*)(C_im + base + 4);
        const float br[8] = {b0.x, b0.y, b0.z, b0.w, b1.x, b1.y, b1.z, b1.w};
        const float bi[8] = {e0.x, e0.y, e0.z, e0.w, e1.x, e1.y, e1.z, e1.w};
        const float cr[8] = {f0.x, f0.y, f0.z, f0.w, f1.x, f1.y, f1.z, f1.w};
        const float ci[8] = {g0.x, g0.y, g0.z, g0.w, g1.x, g1.y, g1.z, g1.w};
        #pragma unroll
        for (int p = 0; p < 4; ++p) {
            CR[p] = (v2){dt * (cr[2*p] * br[2*p] - ci[2*p] * bi[2*p]),
                         dt * (cr[2*p+1] * br[2*p+1] - ci[2*p+1] * bi[2*p+1])};
            CI[p] = (v2){dt * (cr[2*p] * bi[2*p] + ci[2*p] * br[2*p]),
                         dt * (cr[2*p+1] * bi[2*p+1] + ci[2*p+1] * br[2*p+1])};
        }
    }
    const float dpv = Dp[d];
    __syncthreads();   // carries ready

    // ---- phase 3: rescan from carry, contract, store ----
    {
        const float2* cp = &sums[ct * 32 + dd * 16 + h * 8];
        #pragma unroll
        for (int p = 0; p < 4; ++p) {
            float2 c0 = cp[2 * p], c1 = cp[2 * p + 1];
            GR[p] = (v2){c0.x, c1.x};
            GI[p] = (v2){c0.y, c1.y};
        }
    }
    #pragma unroll 4
    for (int ib = 0; ib < T / 2; ++ib) {
        float keep = 0.0f;
        #pragma unroll
        for (int u = 0; u < 2; ++u) {
            int i = ib * 2 + u;
            float xv = xs[i * 256 + ct * 2 + dd];
            v2 XV = (v2){xv, xv};
            v2 ACC = (v2)0;
            #pragma unroll
            for (int p = 0; p < 4; ++p) {
                v2 t2 = vfma(-LI[p], GI[p], XV);
                v2 nr = vfma(LR[p], GR[p], t2);
                GI[p] = vfma(LR[p], GI[p], LI[p] * GR[p]);
                GR[p] = nr;
                ACC = vfma(CR[p], GR[p], ACC);
                ACC = vfma(-CI[p], GI[p], ACC);
            }
            float acc = ACC.x + ACC.y;
            acc += __shfl_xor(acc, 1);    // combine the two n-halves
            acc = fmaf(dpv, xv, acc);
            keep = (h == u) ? acc : keep; // lane h keeps row parity u==h
        }
        out[(size_t)(ct * T + ib * 2 + h) * D + d] = keep;  // all lanes store
    }
}

extern "C" void kernel_launch(void* const* d_in, const int* in_sizes, int n_in,
                              void* d_out, int out_size, void* d_ws, size_t ws_size,
                              hipStream_t stream) {
    const float* x     = (const float*)d_in[0];
    const float* Delta = (const float*)d_in[1];
    const float* A_re  = (const float*)d_in[2];
    const float* A_im  = (const float*)d_in[3];
    const float* B_re  = (const float*)d_in[4];
    const float* B_im  = (const float*)d_in[5];
    const float* C_re  = (const float*)d_in[6];
    const float* C_im  = (const float*)d_in[7];
    const float* Dp    = (const float*)d_in[8];
    float* out = (float*)d_out;

    k_fused<<<NB, NT, 0, stream>>>(x, Delta, A_re, A_im, B_re, B_im,
                                   C_re, C_im, Dp, out);
}

// Round 13
// 102.758 us; speedup vs baseline: 1.2252x; 1.0315x over previous
//
#include <hip/hip_runtime.h>
#include <math.h>

// Problem constants
constexpr int L   = 4096;   // seq len
constexpr int D   = 1024;   // d_model
constexpr int N   = 16;     // hiddens per channel
constexpr int CPB = 4;      // channels per block
constexpr int NB  = D / CPB;   // 256 blocks (1 per CU)
constexpr int NCB = 128;    // chunks per block
constexpr int T   = L / NCB;   // 32 steps per chunk
constexpr int NT  = 1024;   // threads per block (16 waves, 4/SIMD)

typedef float v2 __attribute__((ext_vector_type(2)));

__device__ __forceinline__ float softplus_f(float v) {
    return fmaxf(v, 0.0f) + log1pf(expf(-fabsf(v)));
}

// Fast Lambda = exp(dt*(ar + i*ai)) via HW transcendentals.
__device__ __forceinline__ void lam_fast(float ar, float ai, float dt,
                                         float& lr, float& li) {
    float e = __expf(ar * dt);
    float s, c;
    __sincosf(ai * dt, &s, &c);
    lr = e * c;
    li = e * s;
}

__device__ __forceinline__ v2 vfma(v2 a, v2 b, v2 c) {
    return __builtin_elementwise_fma(a, b, c);
}

// One dispatch, 256 blocks (1/CU). Block owns channels [d0, d0+4) x full L.
// Thread t: h = t&1 (n-half, 8 states), dd = (t>>1)&3 (channel), ct = t>>3
// (chunk of T=32). All cross-thread dataflow is intra-block (LDS + shfl).
//   0) stage x slice via float4 loads (16 B/lane)   -> xs[i][ct][dd], 64 KB
//   1) local scan of chunk ct (packed fp32)         -> sums[ct][dd*16+n]
//   2) wave 0 (64 lanes = all (dd,n) pairs): serial scan over 128 summaries
//   3) rescan from carry, contract C'=dt*C*B, h-shfl reduce, then 4-lane
//      in-register transpose (3 shfl_xor) -> one float4 row-segment store
//      per lane (16 B/lane, fully-packed store granularity)
// d0 swizzle: blocks b, b+8, b+16, b+24 (same XCD under round-robin) share
// each 64 B x-line -> HBM fetch stays ~16 MB, reuse served by that XCD's L2.
__global__ __launch_bounds__(NT, 4) void k_fused(
    const float* __restrict__ x,
    const float* __restrict__ Delta,
    const float* __restrict__ A_re, const float* __restrict__ A_im,
    const float* __restrict__ B_re, const float* __restrict__ B_im,
    const float* __restrict__ C_re, const float* __restrict__ C_im,
    const float* __restrict__ Dp,
    float* __restrict__ out)
{
    __shared__ float  xs[T * 512];        // [i][ct][dd]: word i*512+ct*4+dd
    __shared__ float2 sums[NCB * 64];     // [ct][dd*16+n], 64 KB

    const int b  = blockIdx.x;
    const int d0 = (b & 7) * 128 + (b >> 3) * 4;   // XCD-contiguous channels
    const int t  = threadIdx.x;

    // ---- phase 0: stage x[0..L) x [d0, d0+4) into LDS, float4 loads ----
    {
        const int sct = t & 127;          // chunk
        const int si  = t >> 7;           // 0..7: which 4-row group
        float4 v[4];
        #pragma unroll
        for (int k = 0; k < 4; ++k) {
            int l = sct * T + si * 4 + k;
            v[k] = *(const float4*)(x + (size_t)l * D + d0);
        }
        #pragma unroll
        for (int k = 0; k < 4; ++k)
            *(float4*)&xs[(si * 4 + k) * 512 + sct * 4] = v[k];
    }

    const int h  = t & 1;
    const int dd = (t >> 1) & 3;
    const int ct = t >> 3;
    const int d  = d0 + dd;
    const float dt = softplus_f(Delta[d]);

    // ---- per-thread Lambda for its 8 states (n = h*8..h*8+7), packed ----
    v2 LR[4], LI[4];
    {
        const int base = d * N + h * 8;
        float4 a0 = *(const float4*)(A_re + base);
        float4 a1 = *(const float4*)(A_re + base + 4);
        float4 m0 = *(const float4*)(A_im + base);
        float4 m1 = *(const float4*)(A_im + base + 4);
        const float ar[8] = {a0.x, a0.y, a0.z, a0.w, a1.x, a1.y, a1.z, a1.w};
        const float ai[8] = {m0.x, m0.y, m0.z, m0.w, m1.x, m1.y, m1.z, m1.w};
        #pragma unroll
        for (int p = 0; p < 4; ++p) {
            float lr0, li0, lr1, li1;
            lam_fast(ar[2 * p], ai[2 * p], dt, lr0, li0);
            lam_fast(ar[2 * p + 1], ai[2 * p + 1], dt, lr1, li1);
            LR[p] = (v2){lr0, lr1};
            LI[p] = (v2){li0, li1};
        }
    }
    __syncthreads();   // xs ready

    // ---- phase 1: local scan of chunk ct, zero init ----
    v2 GR[4] = {(v2)0, (v2)0, (v2)0, (v2)0};
    v2 GI[4] = {(v2)0, (v2)0, (v2)0, (v2)0};
    #pragma unroll 4
    for (int i = 0; i < T; ++i) {
        float xv = xs[i * 512 + ct * 4 + dd];
        v2 XV = (v2){xv, xv};
        #pragma unroll
        for (int p = 0; p < 4; ++p) {
            v2 t2 = vfma(-LI[p], GI[p], XV);
            v2 nr = vfma(LR[p], GR[p], t2);
            GI[p] = vfma(LR[p], GI[p], LI[p] * GR[p]);
            GR[p] = nr;
        }
    }
    {
        float2* sp = &sums[ct * 64 + dd * 16 + h * 8];
        #pragma unroll
        for (int p = 0; p < 4; ++p) {
            sp[2 * p]     = make_float2(GR[p].x, GI[p].x);
            sp[2 * p + 1] = make_float2(GR[p].y, GI[p].y);
        }
    }
    __syncthreads();   // summaries ready

    // ---- phase 2: serial scan over chunk summaries (wave 0, 64 lanes) ----
    if (t < 64) {
        const int dd2 = t >> 4, n2 = t & 15;
        const int d2  = d0 + dd2;
        const float dt2 = softplus_f(Delta[d2]);
        float lr, li;
        lam_fast(A_re[d2 * N + n2], A_im[d2 * N + n2], dt2, lr, li);
        #pragma unroll
        for (int k = 0; k < 5; ++k) {     // Lam^32 (T = 32)
            float nr = lr * lr - li * li;
            li = 2.0f * lr * li;
            lr = nr;
        }
        float cr = 0.0f, ci = 0.0f;
        #pragma unroll
        for (int c0 = 0; c0 < NCB; c0 += 16) {
            float2 sv[16];
            #pragma unroll
            for (int u = 0; u < 16; ++u) sv[u] = sums[(c0 + u) * 64 + t];
            #pragma unroll
            for (int u = 0; u < 16; ++u) {
                sums[(c0 + u) * 64 + t] = make_float2(cr, ci);
                float nr = fmaf(lr, cr, fmaf(-li, ci, sv[u].x));
                ci = fmaf(lr, ci, fmaf(li, cr, sv[u].y));
                cr = nr;
            }
        }
    }

    // ---- phase 3 params: C' = dt*(C*B), D (packed) ----
    v2 CR[4], CI[4];
    {
        const int base = d * N + h * 8;
        float4 b0 = *(const float4*)(B_re + base);
        float4 b1 = *(const float4*)(B_re + base + 4);
        float4 e0 = *(const float4*)(B_im + base);
        float4 e1 = *(const float4*)(B_im + base + 4);
        float4 f0 = *(const float4*)(C_re + base);
        float4 f1 = *(const float4*)(C_re + base + 4);
        float4 g0 = *(const float4*)(C_im + base);
        float4 g1 = *(const float4*)(C_im + base + 4);
        const float br[8] = {b0.x, b0.y, b0.z, b0.w, b1.x, b1.y, b1.z, b1.w};
        const float bi[8] = {e0.x, e0.y, e0.z, e0.w, e1.x, e1.y, e1.z, e1.w};
        const float cr[8] = {f0.x, f0.y, f0.z, f0.w, f1.x, f1.y, f1.z, f1.w};
        const float ci[8] = {g0.x, g0.y, g0.z, g0.w, g1.x, g1.y, g1.z, g1.w};
        #pragma unroll
        for (int p = 0; p < 4; ++p) {
            CR[p] = (v2){dt * (cr[2*p] * br[2*p] - ci[2*p] * bi[2*p]),
                         dt * (cr[2*p+1] * br[2*p+1] - ci[2*p+1] * bi[2*p+1])};
            CI[p] = (v2){dt * (cr[2*p] * bi[2*p] + ci[2*p] * br[2*p]),
                         dt * (cr[2*p+1] * bi[2*p+1] + ci[2*p+1] * br[2*p+1])};
        }
    }
    const float dpv = Dp[d];
    __syncthreads();   // carries ready

    // ---- phase 3: rescan from carry, contract, transpose-store ----
    {
        const float2* cp = &sums[ct * 64 + dd * 16 + h * 8];
        #pragma unroll
        for (int p = 0; p < 4; ++p) {
            float2 c0 = cp[2 * p], c1 = cp[2 * p + 1];
            GR[p] = (v2){c0.x, c1.x};
            GI[p] = (v2){c0.y, c1.y};
        }
    }
    #pragma unroll
    for (int ob = 0; ob < T / 8; ++ob) {
        float Vh[4];
        #pragma unroll
        for (int ib = 0; ib < 4; ++ib) {
            #pragma unroll
            for (int u = 0; u < 2; ++u) {
                int i = ob * 8 + ib * 2 + u;
                float xv = xs[i * 512 + ct * 4 + dd];
                v2 XV = (v2){xv, xv};
                v2 ACC = (v2)0;
                #pragma unroll
                for (int p = 0; p < 4; ++p) {
                    v2 t2 = vfma(-LI[p], GI[p], XV);
                    v2 nr = vfma(LR[p], GR[p], t2);
                    GI[p] = vfma(LR[p], GI[p], LI[p] * GR[p]);
                    GR[p] = nr;
                    ACC = vfma(CR[p], GR[p], ACC);
                    ACC = vfma(-CI[p], GI[p], ACC);
                }
                float acc = ACC.x + ACC.y;
                acc += __shfl_xor(acc, 1);       // combine the two n-halves
                acc = fmaf(dpv, xv, acc);        // finished value for (row,col d)
                if (u == h) Vh[ib] = acc;        // lane keeps its row parity
            }
        }
        // 4-lane transpose over dd (lane bits 1..2): lane (h,dd) assembles the
        // full 4-channel segment of row rr = ob*8 + dd*2 + h.
        // shfl_xor(Vh[dd^k], mask k<<1): partner dd^k sends Vh[(dd^k)^k == my dd].
        float f[4];
        f[dd]     = Vh[dd];
        f[dd ^ 1] = __shfl_xor(Vh[dd ^ 1], 2);
        f[dd ^ 2] = __shfl_xor(Vh[dd ^ 2], 4);
        f[dd ^ 3] = __shfl_xor(Vh[dd ^ 3], 6);
        int row = ct * T + ob * 8 + dd * 2 + h;
        *(float4*)(out + (size_t)row * D + d0) =
            make_float4(f[0], f[1], f[2], f[3]);   // 16 B/lane store
    }
}

extern "C" void kernel_launch(void* const* d_in, const int* in_sizes, int n_in,
                              void* d_out, int out_size, void* d_ws, size_t ws_size,
                              hipStream_t stream) {
    const float* x     = (const float*)d_in[0];
    const float* Delta = (const float*)d_in[1];
    const float* A_re  = (const float*)d_in[2];
    const float* A_im  = (const float*)d_in[3];
    const float* B_re  = (const float*)d_in[4];
    const float* B_im  = (const float*)d_in[5];
    const float* C_re  = (const float*)d_in[6];
    const float* C_im  = (const float*)d_in[7];
    const float* Dp    = (const float*)d_in[8];
    float* out = (float*)d_out;

    k_fused<<<NB, NT, 0, stream>>>(x, Delta, A_re, A_im, B_re, B_im,
                                   C_re, C_im, Dp, out);
}